// Round 13
// baseline (186.833 us; speedup 1.0000x reference)
//
#include <hip/hip_runtime.h>
#include <math.h>

#define SS 2048
#define DD 1024
#define HH 16
#define NQKV 3072
#define MROWS 4096
#define KD 1024

typedef __attribute__((ext_vector_type(8))) short bf16x8;
typedef __attribute__((ext_vector_type(8))) unsigned short us8;
typedef __attribute__((ext_vector_type(4))) float f32x4;
typedef __attribute__((ext_vector_type(16))) float f32x16;
typedef unsigned short u16;
typedef unsigned int u32;

#define SCALE_C 0.18033688011112042f  // log2(e)/sqrt(64), folded into Q at GEMM epilogue

// async global->LDS, 16B per lane; LDS dst = wave-uniform base + lane*16
#define GLDS16(g, l) \
  __builtin_amdgcn_global_load_lds((const __attribute__((address_space(1))) u32*)(g), \
                                   (__attribute__((address_space(3))) u32*)(l), 16, 0, 0)

static __device__ __forceinline__ u16 f2bf(float f) {
  union { float f; u32 u; } v; v.f = f;
  u32 u = v.u;
  u += 0x7fffu + ((u >> 16) & 1u);   // RNE
  return (u16)(u >> 16);
}
static __device__ __forceinline__ u32 pk2(float a, float b) {      // RNE pack
  return (u32)f2bf(a) | ((u32)f2bf(b) << 16);
}
static __device__ __forceinline__ u32 pk2t(float a, float b) {     // truncating pack, 1 v_perm
  union { float f; u32 u; } ua, ub; ua.f = a; ub.f = b;
  return __builtin_amdgcn_perm(ub.u, ua.u, 0x07060302u);
}

// ---- merged prep: x convert (blocks 0..2047), w_qkv T (2048..2815), w_proj T (2816..3071) ----
__global__ __launch_bounds__(256) void k_prep(const float* __restrict__ x,
                                              const float* __restrict__ w_qkv,
                                              const float* __restrict__ w_proj,
                                              u16* __restrict__ x_bf,
                                              u16* __restrict__ wqkvT,
                                              u16* __restrict__ wprojT) {
  __shared__ float t[64][65];
  int bx = blockIdx.x;
  int tid = threadIdx.x;
  if (bx < 2048) {
    int i = (bx * 256 + tid) * 8;
    float4 a = *(const float4*)(x + i);
    float4 b = *(const float4*)(x + i + 4);
    us8 o;
    o[0] = f2bf(a.x); o[1] = f2bf(a.y); o[2] = f2bf(a.z); o[3] = f2bf(a.w);
    o[4] = f2bf(b.x); o[5] = f2bf(b.y); o[6] = f2bf(b.z); o[7] = f2bf(b.w);
    *(us8*)(x_bf + i) = o;
    return;
  }
  const float* in; u16* out; int R = KD, C, tile;
  if (bx < 2048 + 768) { in = w_qkv; out = wqkvT; C = NQKV; tile = bx - 2048; }
  else                 { in = w_proj; out = wprojT; C = DD; tile = bx - 2816; }
  int tilesC = C >> 6;
  int tc = tile % tilesC, tr = tile / tilesC;
  int r0 = tr * 64, c0 = tc * 64;
  int lx = tid & 63, ly = tid >> 6;
#pragma unroll
  for (int i = 0; i < 16; i++) {
    int rr = ly + i * 4;
    t[rr][lx] = in[(size_t)(r0 + rr) * C + c0 + lx];
  }
  __syncthreads();
#pragma unroll
  for (int i = 0; i < 16; i++) {
    int cc = ly + i * 4;
    out[(size_t)(c0 + cc) * R + r0 + lx] = f2bf(t[lx][cc]);
  }
}

// ---- bf16 GEMM, r13: BK=32 (64B rows, r7-verified staging) + DOUBLE BUFFER +
// one barrier per k-step, prefetch issued after barrier (r12-verified control flow).
// 32 KB LDS total (BM=128) -> 3 blocks/CU with launch_bounds(256,3).
// MODE 0: f32 out. MODE 2 (BM=128): bf16 qkv out; Q cols (n<1024) pre-scaled by
// SCALE_C; V cols (n>=2048) written ONLY transposed to vt[(b*16+h)*64+d][s]. ----
template <int MODE, int BM>
__global__ __launch_bounds__(256, 3) void k_gemm(const u16* __restrict__ A,
                                                 const u16* __restrict__ Bt,
                                                 const float* __restrict__ bias,
                                                 void* __restrict__ Cout,
                                                 u16* __restrict__ vt,
                                                 int M, int N, int K) {
  constexpr int MT = BM / 32;                  // row-subtiles per wave: 4 or 2
  constexpr int AI = BM / 64;                  // A staging instrs per wave: 2 or 1
  __shared__ alignas(16) u16 As[2][BM * 32];   // dbuf, rows 64B, XOR-swizzled chunks
  __shared__ alignas(16) u16 Bs[2][128 * 32];
  const int tid = threadIdx.x;
  const int w = tid >> 6, ln = tid & 63;
  const int wm = w >> 1, wn = w & 1;
  const int lm = ln & 15, quad = ln >> 4;
  const int m0 = blockIdx.y * BM, n0 = blockIdx.x * 128;
  const int lr = ln >> 2, c = ln & 3;
  const int cg = c ^ (lr & 3);                 // chunk swizzle: stored chunk = real ^ (row&3)

  f32x4 acc[MT][4];
#pragma unroll
  for (int i = 0; i < MT; i++)
#pragma unroll
    for (int j = 0; j < 4; j++) acc[i][j] = (f32x4){0.f, 0.f, 0.f, 0.f};

  const u16* gA = A  + (size_t)(m0 + lr) * K + cg * 8;
  const u16* gB = Bt + (size_t)(n0 + lr) * K + cg * 8;

  // prologue: stage k0=0 into buf 0 (1KB = 16 rows of 64B per instr)
#pragma unroll
  for (int ii = 0; ii < AI; ii++) {
    int i = w + 4 * ii;
    GLDS16(gA + (size_t)(16 * i) * K, (char*)As[0] + i * 1024);
  }
#pragma unroll
  for (int ii = 0; ii < 2; ii++) {
    int i = w + 4 * ii;
    GLDS16(gB + (size_t)(16 * i) * K, (char*)Bs[0] + i * 1024);
  }

  for (int k0 = 0; k0 < K; k0 += 32) {
    __syncthreads();   // drains tile-k0 loads (issued one compute-phase ago)

    if (k0 + 32 < K) {
      char* ad = (char*)As[((k0 >> 5) + 1) & 1];
      char* bd = (char*)Bs[((k0 >> 5) + 1) & 1];
#pragma unroll
      for (int ii = 0; ii < AI; ii++) {
        int i = w + 4 * ii;
        GLDS16(gA + (size_t)(16 * i) * K + k0 + 32, ad + i * 1024);
      }
#pragma unroll
      for (int ii = 0; ii < 2; ii++) {
        int i = w + 4 * ii;
        GLDS16(gB + (size_t)(16 * i) * K + k0 + 32, bd + i * 1024);
      }
    }

    const char* asb = (const char*)As[(k0 >> 5) & 1];
    const char* bsb = (const char*)Bs[(k0 >> 5) & 1];

    bf16x8 af[MT], bfr[4];
#pragma unroll
    for (int t = 0; t < MT; t++)
      af[t] = *(const bf16x8*)(asb + (wm * (MT * 16) + t * 16 + lm) * 64 + ((quad ^ (lm & 3)) * 16));
#pragma unroll
    for (int t = 0; t < 4; t++)
      bfr[t] = *(const bf16x8*)(bsb + (wn * 64 + t * 16 + lm) * 64 + ((quad ^ (lm & 3)) * 16));
#pragma unroll
    for (int mt = 0; mt < MT; mt++)
#pragma unroll
      for (int nt = 0; nt < 4; nt++)
        acc[mt][nt] = __builtin_amdgcn_mfma_f32_16x16x32_bf16(af[mt], bfr[nt], acc[mt][nt], 0, 0, 0);
  }

  float bv[4];
#pragma unroll
  for (int nt = 0; nt < 4; nt++) bv[nt] = bias[n0 + wn * 64 + nt * 16 + lm];

  if (MODE == 2 && n0 >= 2 * DD) {
    // V tile: write transposed to vt. All rows of this tile share b.
    int b = m0 >> 11;
    int s0 = (m0 & 2047) + wm * 64;
#pragma unroll
    for (int mt = 0; mt < MT; mt++) {
      int s = s0 + mt * 16 + quad * 4;
#pragma unroll
      for (int nt = 0; nt < 4; nt++) {
        int n = n0 + wn * 64 + nt * 16 + lm;
        int bh = b * HH + ((n - 2 * DD) >> 6);
        int d = n & 63;
        uint2 v;
        v.x = pk2(acc[mt][nt][0] + bv[nt], acc[mt][nt][1] + bv[nt]);
        v.y = pk2(acc[mt][nt][2] + bv[nt], acc[mt][nt][3] + bv[nt]);
        *(uint2*)&vt[(size_t)(bh * 64 + d) * SS + s] = v;
      }
    }
    return;
  }

  const float qs = (MODE == 2 && n0 < DD) ? SCALE_C : 1.0f;  // fold softmax scale into Q
#pragma unroll
  for (int mt = 0; mt < MT; mt++) {
#pragma unroll
    for (int r = 0; r < 4; r++) {
      int row = m0 + wm * (MT * 16) + mt * 16 + quad * 4 + r;
#pragma unroll
      for (int nt = 0; nt < 4; nt++) {
        int col = n0 + wn * 64 + nt * 16 + lm;
        float v = (acc[mt][nt][r] + bv[nt]) * qs;
        if (MODE == 2) ((u16*)Cout)[(size_t)row * N + col] = f2bf(v);
        else           ((float*)Cout)[(size_t)row * N + col] = v;
      }
    }
  }
}

// ---- flash attention (r11, unchanged): 32x32x16 MFMA, register P-transpose,
//      128-key dbuf tiles, 1 barrier/tile, LDS 64 KB -> 2 blocks/CU. ----
__global__ __launch_bounds__(256, 2) void k_attn(const u16* __restrict__ qkv,
                                                 const u16* __restrict__ vt,
                                                 u16* __restrict__ attn) {
  __shared__ alignas(16) u16 Ks[2][128 * 64];   // dbuf [key][d], 128B rows
  __shared__ alignas(16) u16 Vs[2][64 * 128];   // dbuf [d][key], 256B rows

  const int tid = threadIdx.x;
  const int w = tid >> 6, ln = tid & 63;
  const int qn = ln & 31, h5 = ln >> 5;         // lane's q-index / k-half
  const int bx = blockIdx.x;
  const int bh = bx >> 4;
  const int q0 = (bx & 15) * 128;
  const int b = bh >> 4, h = bh & 15;
  const size_t qkv_b = (size_t)b * SS * NQKV;
  const int hcol = h * 64;

  const int lr = ln >> 3, cc = ln & 7;
  const int cg = cc ^ lr;                  // K-staging chunk swizzle (row&7)
  const int vr = ln >> 4, c16 = ln & 15;   // V-staging: 4 rows x 16 chunks per 1KB

  // Q B-fragments direct from global: B[k=d][n=q], d = 16*ks + 8*h5 + j
  bf16x8 qf[4];
  {
    const u16* qp = qkv + qkv_b + (size_t)(q0 + w * 32 + qn) * NQKV + hcol + h5 * 8;
#pragma unroll
    for (int ks = 0; ks < 4; ks++) qf[ks] = *(const bf16x8*)(qp + ks * 16);
  }

  f32x16 o[2];
#pragma unroll
  for (int i = 0; i < 16; i++) { o[0][i] = 0.f; o[1][i] = 0.f; }
  float lsum = 0.f;

  // stage K/V tile 0 (128 keys) into buf 0: 16 x 1KB each of K and V
#pragma unroll
  for (int rr = 0; rr < 4; rr++) {
    int i = w + 4 * rr;
    GLDS16(qkv + qkv_b + (size_t)(8 * i + lr) * NQKV + DD + hcol + cg * 8, (char*)Ks[0] + i * 1024);
    int cgv = c16 ^ ((4 * i + vr) & 15);
    GLDS16(vt + (size_t)(bh * 64 + 4 * i + vr) * SS + cgv * 8,             (char*)Vs[0] + i * 1024);
  }

#pragma unroll 1
  for (int it = 0; it < SS / 128; it++) {
    __syncthreads();   // drains tile-it loads (issued one compute-phase ago)

    if (it + 1 < SS / 128) {
      int kv1 = (it + 1) * 128;
      char* kd = (char*)Ks[(it + 1) & 1];
      char* vd = (char*)Vs[(it + 1) & 1];
#pragma unroll
      for (int rr = 0; rr < 4; rr++) {
        int i = w + 4 * rr;
        GLDS16(qkv + qkv_b + (size_t)(kv1 + 8 * i + lr) * NQKV + DD + hcol + cg * 8, kd + i * 1024);
        int cgv = c16 ^ ((4 * i + vr) & 15);
        GLDS16(vt + (size_t)(bh * 64 + 4 * i + vr) * SS + kv1 + cgv * 8,             vd + i * 1024);
      }
    }

    const char* ksb = (const char*)Ks[it & 1];
    const char* vsb = (const char*)Vs[it & 1];

    // two 64-key halves per staged tile
#pragma unroll
    for (int sub = 0; sub < 2; sub++) {
      // S^T[key][q] = K · Q^T, two 32-key m-subtiles, 4 k-steps of 16 over d
      f32x16 s0, s1;
#pragma unroll
      for (int i = 0; i < 16; i++) { s0[i] = 0.f; s1[i] = 0.f; }
#pragma unroll
      for (int ks = 0; ks < 4; ks++) {
        int ch = 2 * ks + h5;
        bf16x8 kf0 = *(const bf16x8*)(ksb + (sub * 64 + qn) * 128 + ((ch ^ (qn & 7)) * 16));
        bf16x8 kf1 = *(const bf16x8*)(ksb + (sub * 64 + 32 + qn) * 128 + ((ch ^ (qn & 7)) * 16));
        s0 = __builtin_amdgcn_mfma_f32_32x32x16_bf16(kf0, qf[ks], s0, 0, 0, 0);
        s1 = __builtin_amdgcn_mfma_f32_32x32x16_bf16(kf1, qf[ks], s1, 0, 0, 0);
      }

      // V A-fragments hoisted: A[m=d][k=key], d = dm*32+qn, key = sub*64+16*ks2+8*h5+j
      bf16x8 vf[2][4];
#pragma unroll
      for (int dm = 0; dm < 2; dm++)
#pragma unroll
        for (int ks2 = 0; ks2 < 4; ks2++) {
          int d = dm * 32 + qn;
          int ch16 = 8 * sub + 2 * ks2 + h5;
          vf[dm][ks2] = *(const bf16x8*)(vsb + d * 256 + ((ch16 ^ (qn & 15)) * 16));
        }

      // softmax numerators: p = 2^s, lane-local; pack to bf16 pairs.
      u32 pk0[4][2], pk1[4][2];
      float sum = 0.f;
#pragma unroll
      for (int g = 0; g < 4; g++) {
        float a0 = __builtin_amdgcn_exp2f(s0[4 * g]);
        float a1 = __builtin_amdgcn_exp2f(s0[4 * g + 1]);
        float a2 = __builtin_amdgcn_exp2f(s0[4 * g + 2]);
        float a3 = __builtin_amdgcn_exp2f(s0[4 * g + 3]);
        float b0 = __builtin_amdgcn_exp2f(s1[4 * g]);
        float b1 = __builtin_amdgcn_exp2f(s1[4 * g + 1]);
        float b2 = __builtin_amdgcn_exp2f(s1[4 * g + 2]);
        float b3 = __builtin_amdgcn_exp2f(s1[4 * g + 3]);
        sum += ((a0 + a1) + (a2 + a3)) + ((b0 + b1) + (b2 + b3));
        pk0[g][0] = pk2t(a0, a1); pk0[g][1] = pk2t(a2, a3);
        pk1[g][0] = pk2t(b0, b1); pk1[g][1] = pk2t(b2, b3);
      }
      lsum += sum;

      // C-layout -> B-layout in registers (sender-side h5-uniform select + xor32)
      bf16x8 pf[4];
#pragma unroll
      for (int blk = 0; blk < 2; blk++) {
#pragma unroll
        for (int ks = 0; ks < 2; ks++) {
          u32 e0 = blk ? pk1[2 * ks][0]     : pk0[2 * ks][0];
          u32 e1 = blk ? pk1[2 * ks][1]     : pk0[2 * ks][1];
          u32 o0 = blk ? pk1[2 * ks + 1][0] : pk0[2 * ks + 1][0];
          u32 o1 = blk ? pk1[2 * ks + 1][1] : pk0[2 * ks + 1][1];
          u32 s0v = h5 ? e0 : o0;            // what the ^32 partner needs
          u32 s1v = h5 ? e1 : o1;
          u32 r0 = (u32)__shfl_xor((int)s0v, 32);
          u32 r1 = (u32)__shfl_xor((int)s1v, 32);
          union { u32 u[4]; bf16x8 v; } f;
          f.u[0] = h5 ? r0 : e0;
          f.u[1] = h5 ? r1 : e1;
          f.u[2] = h5 ? o0 : r0;
          f.u[3] = h5 ? o1 : r1;
          pf[blk * 2 + ks] = f.v;
        }
      }

      // O^T[d][q] += V^T · P^T
#pragma unroll
      for (int ks2 = 0; ks2 < 4; ks2++) {
        o[0] = __builtin_amdgcn_mfma_f32_32x32x16_bf16(vf[0][ks2], pf[ks2], o[0], 0, 0, 0);
        o[1] = __builtin_amdgcn_mfma_f32_32x32x16_bf16(vf[1][ks2], pf[ks2], o[1], 0, 0, 0);
      }
    }
  }

  // finalize: single cross-lane reduction for l, then normalize + store.
  lsum += __shfl_xor(lsum, 32);
  float il = 1.0f / lsum;
  int row = b * SS + q0 + w * 32 + qn;
#pragma unroll
  for (int dm = 0; dm < 2; dm++)
#pragma unroll
    for (int g = 0; g < 4; g++) {
      int d = dm * 32 + 8 * g + 4 * h5;
      uint2 v;
      v.x = pk2(o[dm][4 * g] * il, o[dm][4 * g + 1] * il);
      v.y = pk2(o[dm][4 * g + 2] * il, o[dm][4 * g + 3] * il);
      *(uint2*)&attn[(size_t)row * DD + hcol + d] = v;
    }
}

extern "C" void kernel_launch(void* const* d_in, const int* in_sizes, int n_in,
                              void* d_out, int out_size, void* d_ws, size_t ws_size,
                              hipStream_t stream) {
  const float* x      = (const float*)d_in[0];
  const float* w_qkv  = (const float*)d_in[1];
  const float* b_qkv  = (const float*)d_in[2];
  const float* w_proj = (const float*)d_in[3];
  const float* b_proj = (const float*)d_in[4];
  float* out = (float*)d_out;

  u16* ws     = (u16*)d_ws;
  u16* x_bf   = ws;                                  // 4M u16
  u16* wqkvT  = x_bf   + (size_t)MROWS * KD;         // 3M
  u16* wprojT = wqkvT  + (size_t)NQKV * KD;          // 1M
  u16* qkv    = wprojT + (size_t)DD * KD;            // 12M (V region unused)
  u16* attn   = qkv    + (size_t)MROWS * NQKV;       // 4M
  u16* vt     = attn   + (size_t)MROWS * DD;         // 4M

  k_prep<<<3072, 256, 0, stream>>>(x, w_qkv, w_proj, x_bf, wqkvT, wprojT);
  k_gemm<2, 128><<<dim3(NQKV / 128, MROWS / 128), 256, 0, stream>>>(x_bf, wqkvT, b_qkv, qkv, vt, MROWS, NQKV, KD);
  k_attn<<<2 * HH * (SS / 128), 256, 0, stream>>>(qkv, vt, attn);
  k_gemm<0, 64><<<dim3(DD / 128, MROWS / 64), 256, 0, stream>>>(attn, wprojT, b_proj, out, nullptr, MROWS, DD, KD);
}

// Round 14
// 173.784 us; speedup vs baseline: 1.0751x; 1.0751x over previous
//
#include <hip/hip_runtime.h>
#include <math.h>

#define SS 2048
#define DD 1024
#define HH 16
#define NQKV 3072
#define MROWS 4096
#define KD 1024

typedef __attribute__((ext_vector_type(8))) short bf16x8;
typedef __attribute__((ext_vector_type(8))) unsigned short us8;
typedef __attribute__((ext_vector_type(4))) float f32x4;
typedef __attribute__((ext_vector_type(16))) float f32x16;
typedef unsigned short u16;
typedef unsigned int u32;

#define SCALE_C 0.18033688011112042f  // log2(e)/sqrt(64), folded into Q at GEMM epilogue

// async global->LDS, 16B per lane; LDS dst = wave-uniform base + lane*16
#define GLDS16(g, l) \
  __builtin_amdgcn_global_load_lds((const __attribute__((address_space(1))) u32*)(g), \
                                   (__attribute__((address_space(3))) u32*)(l), 16, 0, 0)

static __device__ __forceinline__ u16 f2bf(float f) {
  union { float f; u32 u; } v; v.f = f;
  u32 u = v.u;
  u += 0x7fffu + ((u >> 16) & 1u);   // RNE
  return (u16)(u >> 16);
}
static __device__ __forceinline__ u32 pk2(float a, float b) {      // RNE pack
  return (u32)f2bf(a) | ((u32)f2bf(b) << 16);
}
static __device__ __forceinline__ u32 pk2t(float a, float b) {     // truncating pack, 1 v_perm
  union { float f; u32 u; } ua, ub; ua.f = a; ub.f = b;
  return __builtin_amdgcn_perm(ub.u, ua.u, 0x07060302u);
}

// ---- merged prep: x convert (blocks 0..2047), w_qkv T (2048..2815), w_proj T (2816..3071) ----
__global__ __launch_bounds__(256) void k_prep(const float* __restrict__ x,
                                              const float* __restrict__ w_qkv,
                                              const float* __restrict__ w_proj,
                                              u16* __restrict__ x_bf,
                                              u16* __restrict__ wqkvT,
                                              u16* __restrict__ wprojT) {
  __shared__ float t[64][65];
  int bx = blockIdx.x;
  int tid = threadIdx.x;
  if (bx < 2048) {
    int i = (bx * 256 + tid) * 8;
    float4 a = *(const float4*)(x + i);
    float4 b = *(const float4*)(x + i + 4);
    us8 o;
    o[0] = f2bf(a.x); o[1] = f2bf(a.y); o[2] = f2bf(a.z); o[3] = f2bf(a.w);
    o[4] = f2bf(b.x); o[5] = f2bf(b.y); o[6] = f2bf(b.z); o[7] = f2bf(b.w);
    *(us8*)(x_bf + i) = o;
    return;
  }
  const float* in; u16* out; int R = KD, C, tile;
  if (bx < 2048 + 768) { in = w_qkv; out = wqkvT; C = NQKV; tile = bx - 2048; }
  else                 { in = w_proj; out = wprojT; C = DD; tile = bx - 2816; }
  int tilesC = C >> 6;
  int tc = tile % tilesC, tr = tile / tilesC;
  int r0 = tr * 64, c0 = tc * 64;
  int lx = tid & 63, ly = tid >> 6;
#pragma unroll
  for (int i = 0; i < 16; i++) {
    int rr = ly + i * 4;
    t[rr][lx] = in[(size_t)(r0 + rr) * C + c0 + lx];
  }
  __syncthreads();
#pragma unroll
  for (int i = 0; i < 16; i++) {
    int cc = ly + i * 4;
    out[(size_t)(c0 + cc) * R + r0 + lx] = f2bf(t[lx][cc]);
  }
}

// ---- bf16 GEMM, r8-exact (best measured): BK=64, SINGLE-buffer 32KB LDS,
// two barriers per k-step, 3 blocks/CU TLP hides the staging drain.
// MODE 0: f32 out. MODE 2 (BM=128): bf16 qkv out; Q cols (n<1024) pre-scaled by
// SCALE_C; V cols (n>=2048) written ONLY transposed to vt[(b*16+h)*64+d][s]. ----
template <int MODE, int BM>
__global__ __launch_bounds__(256, 2) void k_gemm(const u16* __restrict__ A,
                                                 const u16* __restrict__ Bt,
                                                 const float* __restrict__ bias,
                                                 void* __restrict__ Cout,
                                                 u16* __restrict__ vt,
                                                 int M, int N, int K) {
  constexpr int MT = BM / 32;                // row-subtiles per wave: 4 or 2
  __shared__ alignas(16) u16 As[BM * 64];    // rows 128B, XOR-swizzled 16B chunks
  __shared__ alignas(16) u16 Bs[128 * 64];
  const int tid = threadIdx.x;
  const int w = tid >> 6, ln = tid & 63;
  const int wm = w >> 1, wn = w & 1;
  const int lm = ln & 15, quad = ln >> 4;
  const int m0 = blockIdx.y * BM, n0 = blockIdx.x * 128;
  const int lr = ln >> 3, cc = ln & 7;
  const int cg = cc ^ lr;                    // chunk swizzle: stored chunk = real ^ (row&7)

  f32x4 acc[MT][4];
#pragma unroll
  for (int i = 0; i < MT; i++)
#pragma unroll
    for (int j = 0; j < 4; j++) acc[i][j] = (f32x4){0.f, 0.f, 0.f, 0.f};

  const u16* gA = A  + (size_t)(m0 + lr) * K + cg * 8;
  const u16* gB = Bt + (size_t)(n0 + lr) * K + cg * 8;

  for (int k0 = 0; k0 < K; k0 += 64) {
    // stage A (BM rows x 128B) + B (128 rows x 128B); 1KB (8 rows) per instr
#pragma unroll
    for (int ii = 0; ii < MT; ii++) {
      int i = w + 4 * ii;
      GLDS16(gA + (size_t)(8 * i) * K + k0, (char*)As + i * 1024);
    }
#pragma unroll
    for (int ii = 0; ii < 4; ii++) {
      int i = w + 4 * ii;
      GLDS16(gB + (size_t)(8 * i) * K + k0, (char*)Bs + i * 1024);
    }
    __syncthreads();
    bf16x8 af[MT][2], bfr[4][2];
#pragma unroll
    for (int t = 0; t < MT; t++)
#pragma unroll
      for (int kk = 0; kk < 2; kk++)
        af[t][kk] = *(const bf16x8*)((const char*)As + (wm * (MT * 16) + t * 16 + lm) * 128 +
                                     (((kk * 4 + quad) ^ (lm & 7)) * 16));
#pragma unroll
    for (int t = 0; t < 4; t++)
#pragma unroll
      for (int kk = 0; kk < 2; kk++)
        bfr[t][kk] = *(const bf16x8*)((const char*)Bs + (wn * 64 + t * 16 + lm) * 128 +
                                      (((kk * 4 + quad) ^ (lm & 7)) * 16));
#pragma unroll
    for (int kk = 0; kk < 2; kk++)
#pragma unroll
      for (int mt = 0; mt < MT; mt++)
#pragma unroll
        for (int nt = 0; nt < 4; nt++)
          acc[mt][nt] = __builtin_amdgcn_mfma_f32_16x16x32_bf16(af[mt][kk], bfr[nt][kk], acc[mt][nt], 0, 0, 0);
    __syncthreads();
  }

  float bv[4];
#pragma unroll
  for (int nt = 0; nt < 4; nt++) bv[nt] = bias[n0 + wn * 64 + nt * 16 + lm];

  if (MODE == 2 && n0 >= 2 * DD) {
    // V tile: write transposed to vt. All rows of this tile share b.
    int b = m0 >> 11;
    int s0 = (m0 & 2047) + wm * 64;
#pragma unroll
    for (int mt = 0; mt < MT; mt++) {
      int s = s0 + mt * 16 + quad * 4;
#pragma unroll
      for (int nt = 0; nt < 4; nt++) {
        int n = n0 + wn * 64 + nt * 16 + lm;
        int bh = b * HH + ((n - 2 * DD) >> 6);
        int d = n & 63;
        uint2 v;
        v.x = pk2(acc[mt][nt][0] + bv[nt], acc[mt][nt][1] + bv[nt]);
        v.y = pk2(acc[mt][nt][2] + bv[nt], acc[mt][nt][3] + bv[nt]);
        *(uint2*)&vt[(size_t)(bh * 64 + d) * SS + s] = v;
      }
    }
    return;
  }

  const float qs = (MODE == 2 && n0 < DD) ? SCALE_C : 1.0f;  // fold softmax scale into Q
#pragma unroll
  for (int mt = 0; mt < MT; mt++) {
#pragma unroll
    for (int r = 0; r < 4; r++) {
      int row = m0 + wm * (MT * 16) + mt * 16 + quad * 4 + r;
#pragma unroll
      for (int nt = 0; nt < 4; nt++) {
        int col = n0 + wn * 64 + nt * 16 + lm;
        float v = (acc[mt][nt][r] + bv[nt]) * qs;
        if (MODE == 2) ((u16*)Cout)[(size_t)row * N + col] = f2bf(v);
        else           ((float*)Cout)[(size_t)row * N + col] = v;
      }
    }
  }
}

// ---- flash attention (r13-exact): 32x32x16 MFMA, register P-transpose,
//      128-key dbuf tiles, 1 barrier/tile, LDS 64 KB -> 2 blocks/CU. ----
__global__ __launch_bounds__(256, 2) void k_attn(const u16* __restrict__ qkv,
                                                 const u16* __restrict__ vt,
                                                 u16* __restrict__ attn) {
  __shared__ alignas(16) u16 Ks[2][128 * 64];   // dbuf [key][d], 128B rows
  __shared__ alignas(16) u16 Vs[2][64 * 128];   // dbuf [d][key], 256B rows

  const int tid = threadIdx.x;
  const int w = tid >> 6, ln = tid & 63;
  const int qn = ln & 31, h5 = ln >> 5;         // lane's q-index / k-half
  const int bx = blockIdx.x;
  const int bh = bx >> 4;
  const int q0 = (bx & 15) * 128;
  const int b = bh >> 4, h = bh & 15;
  const size_t qkv_b = (size_t)b * SS * NQKV;
  const int hcol = h * 64;

  const int lr = ln >> 3, cc = ln & 7;
  const int cg = cc ^ lr;                  // K-staging chunk swizzle (row&7)
  const int vr = ln >> 4, c16 = ln & 15;   // V-staging: 4 rows x 16 chunks per 1KB

  // Q B-fragments direct from global: B[k=d][n=q], d = 16*ks + 8*h5 + j
  bf16x8 qf[4];
  {
    const u16* qp = qkv + qkv_b + (size_t)(q0 + w * 32 + qn) * NQKV + hcol + h5 * 8;
#pragma unroll
    for (int ks = 0; ks < 4; ks++) qf[ks] = *(const bf16x8*)(qp + ks * 16);
  }

  f32x16 o[2];
#pragma unroll
  for (int i = 0; i < 16; i++) { o[0][i] = 0.f; o[1][i] = 0.f; }
  float lsum = 0.f;

  // stage K/V tile 0 (128 keys) into buf 0: 16 x 1KB each of K and V
#pragma unroll
  for (int rr = 0; rr < 4; rr++) {
    int i = w + 4 * rr;
    GLDS16(qkv + qkv_b + (size_t)(8 * i + lr) * NQKV + DD + hcol + cg * 8, (char*)Ks[0] + i * 1024);
    int cgv = c16 ^ ((4 * i + vr) & 15);
    GLDS16(vt + (size_t)(bh * 64 + 4 * i + vr) * SS + cgv * 8,             (char*)Vs[0] + i * 1024);
  }

#pragma unroll 1
  for (int it = 0; it < SS / 128; it++) {
    __syncthreads();   // drains tile-it loads (issued one compute-phase ago)

    if (it + 1 < SS / 128) {
      int kv1 = (it + 1) * 128;
      char* kd = (char*)Ks[(it + 1) & 1];
      char* vd = (char*)Vs[(it + 1) & 1];
#pragma unroll
      for (int rr = 0; rr < 4; rr++) {
        int i = w + 4 * rr;
        GLDS16(qkv + qkv_b + (size_t)(kv1 + 8 * i + lr) * NQKV + DD + hcol + cg * 8, kd + i * 1024);
        int cgv = c16 ^ ((4 * i + vr) & 15);
        GLDS16(vt + (size_t)(bh * 64 + 4 * i + vr) * SS + kv1 + cgv * 8,             vd + i * 1024);
      }
    }

    const char* ksb = (const char*)Ks[it & 1];
    const char* vsb = (const char*)Vs[it & 1];

    // two 64-key halves per staged tile
#pragma unroll
    for (int sub = 0; sub < 2; sub++) {
      // S^T[key][q] = K · Q^T, two 32-key m-subtiles, 4 k-steps of 16 over d
      f32x16 s0, s1;
#pragma unroll
      for (int i = 0; i < 16; i++) { s0[i] = 0.f; s1[i] = 0.f; }
#pragma unroll
      for (int ks = 0; ks < 4; ks++) {
        int ch = 2 * ks + h5;
        bf16x8 kf0 = *(const bf16x8*)(ksb + (sub * 64 + qn) * 128 + ((ch ^ (qn & 7)) * 16));
        bf16x8 kf1 = *(const bf16x8*)(ksb + (sub * 64 + 32 + qn) * 128 + ((ch ^ (qn & 7)) * 16));
        s0 = __builtin_amdgcn_mfma_f32_32x32x16_bf16(kf0, qf[ks], s0, 0, 0, 0);
        s1 = __builtin_amdgcn_mfma_f32_32x32x16_bf16(kf1, qf[ks], s1, 0, 0, 0);
      }

      // V A-fragments hoisted: A[m=d][k=key], d = dm*32+qn, key = sub*64+16*ks2+8*h5+j
      bf16x8 vf[2][4];
#pragma unroll
      for (int dm = 0; dm < 2; dm++)
#pragma unroll
        for (int ks2 = 0; ks2 < 4; ks2++) {
          int d = dm * 32 + qn;
          int ch16 = 8 * sub + 2 * ks2 + h5;
          vf[dm][ks2] = *(const bf16x8*)(vsb + d * 256 + ((ch16 ^ (qn & 15)) * 16));
        }

      // softmax numerators: p = 2^s, lane-local; pack to bf16 pairs.
      u32 pk0[4][2], pk1[4][2];
      float sum = 0.f;
#pragma unroll
      for (int g = 0; g < 4; g++) {
        float a0 = __builtin_amdgcn_exp2f(s0[4 * g]);
        float a1 = __builtin_amdgcn_exp2f(s0[4 * g + 1]);
        float a2 = __builtin_amdgcn_exp2f(s0[4 * g + 2]);
        float a3 = __builtin_amdgcn_exp2f(s0[4 * g + 3]);
        float b0 = __builtin_amdgcn_exp2f(s1[4 * g]);
        float b1 = __builtin_amdgcn_exp2f(s1[4 * g + 1]);
        float b2 = __builtin_amdgcn_exp2f(s1[4 * g + 2]);
        float b3 = __builtin_amdgcn_exp2f(s1[4 * g + 3]);
        sum += ((a0 + a1) + (a2 + a3)) + ((b0 + b1) + (b2 + b3));
        pk0[g][0] = pk2t(a0, a1); pk0[g][1] = pk2t(a2, a3);
        pk1[g][0] = pk2t(b0, b1); pk1[g][1] = pk2t(b2, b3);
      }
      lsum += sum;

      // C-layout -> B-layout in registers (sender-side h5-uniform select + xor32)
      bf16x8 pf[4];
#pragma unroll
      for (int blk = 0; blk < 2; blk++) {
#pragma unroll
        for (int ks = 0; ks < 2; ks++) {
          u32 e0 = blk ? pk1[2 * ks][0]     : pk0[2 * ks][0];
          u32 e1 = blk ? pk1[2 * ks][1]     : pk0[2 * ks][1];
          u32 o0 = blk ? pk1[2 * ks + 1][0] : pk0[2 * ks + 1][0];
          u32 o1 = blk ? pk1[2 * ks + 1][1] : pk0[2 * ks + 1][1];
          u32 s0v = h5 ? e0 : o0;            // what the ^32 partner needs
          u32 s1v = h5 ? e1 : o1;
          u32 r0 = (u32)__shfl_xor((int)s0v, 32);
          u32 r1 = (u32)__shfl_xor((int)s1v, 32);
          union { u32 u[4]; bf16x8 v; } f;
          f.u[0] = h5 ? r0 : e0;
          f.u[1] = h5 ? r1 : e1;
          f.u[2] = h5 ? o0 : r0;
          f.u[3] = h5 ? o1 : r1;
          pf[blk * 2 + ks] = f.v;
        }
      }

      // O^T[d][q] += V^T · P^T
#pragma unroll
      for (int ks2 = 0; ks2 < 4; ks2++) {
        o[0] = __builtin_amdgcn_mfma_f32_32x32x16_bf16(vf[0][ks2], pf[ks2], o[0], 0, 0, 0);
        o[1] = __builtin_amdgcn_mfma_f32_32x32x16_bf16(vf[1][ks2], pf[ks2], o[1], 0, 0, 0);
      }
    }
  }

  // finalize: single cross-lane reduction for l, then normalize + store.
  lsum += __shfl_xor(lsum, 32);
  float il = 1.0f / lsum;
  int row = b * SS + q0 + w * 32 + qn;
#pragma unroll
  for (int dm = 0; dm < 2; dm++)
#pragma unroll
    for (int g = 0; g < 4; g++) {
      int d = dm * 32 + 8 * g + 4 * h5;
      uint2 v;
      v.x = pk2(o[dm][4 * g] * il, o[dm][4 * g + 1] * il);
      v.y = pk2(o[dm][4 * g + 2] * il, o[dm][4 * g + 3] * il);
      *(uint2*)&attn[(size_t)row * DD + hcol + d] = v;
    }
}

extern "C" void kernel_launch(void* const* d_in, const int* in_sizes, int n_in,
                              void* d_out, int out_size, void* d_ws, size_t ws_size,
                              hipStream_t stream) {
  const float* x      = (const float*)d_in[0];
  const float* w_qkv  = (const float*)d_in[1];
  const float* b_qkv  = (const float*)d_in[2];
  const float* w_proj = (const float*)d_in[3];
  const float* b_proj = (const float*)d_in[4];
  float* out = (float*)d_out;

  u16* ws     = (u16*)d_ws;
  u16* x_bf   = ws;                                  // 4M u16
  u16* wqkvT  = x_bf   + (size_t)MROWS * KD;         // 3M
  u16* wprojT = wqkvT  + (size_t)NQKV * KD;          // 1M
  u16* qkv    = wprojT + (size_t)DD * KD;            // 12M (V region unused)
  u16* attn   = qkv    + (size_t)MROWS * NQKV;       // 4M
  u16* vt     = attn   + (size_t)MROWS * DD;         // 4M

  k_prep<<<3072, 256, 0, stream>>>(x, w_qkv, w_proj, x_bf, wqkvT, wprojT);
  k_gemm<2, 128><<<dim3(NQKV / 128, MROWS / 128), 256, 0, stream>>>(x_bf, wqkvT, b_qkv, qkv, vt, MROWS, NQKV, KD);
  k_attn<<<2 * HH * (SS / 128), 256, 0, stream>>>(qkv, vt, attn);
  k_gemm<0, 64><<<dim3(DD / 128, MROWS / 64), 256, 0, stream>>>(attn, wprojT, b_proj, out, nullptr, MROWS, DD, KD);
}